// Round 1
// baseline (160.876 us; speedup 1.0000x reference)
//
#include <hip/hip_runtime.h>

#define N_NODES 100000
#define N_EDGES 1250000
#define D_FEAT  64

// ---------------- superbin layout ----------------
#define SB_SHIFT 9
#define SB_NODES 512                                   // nodes per superbin
#define NSB      ((N_NODES + SB_NODES - 1) / SB_NODES) // 196
#define SBCAP    7168                                  // mean 6377 + ~10 sigma
#define OVF_CAP  32768

// ---------------- k1 grid ----------------
#define K1_BLOCKS  1024
#define K1_THREADS 512
#define K1_STRIDE  (K1_BLOCKS * K1_THREADS)            // 524288
#define K1_ITERS   ((N_EDGES + K1_STRIDE - 1) / K1_STRIDE) // 3

// ---------------- k23 ----------------
#define NPB   64                                       // nodes per gather block
#define NBLK  ((N_NODES + NPB - 1) / NPB)              // 1563
#define KCAP  1280                                     // kept-list cap (mean 800 + 17 sigma)

// ============ k1: superbin scatter (no scan, no staging) ============
// LDS histogram over 196 superbins -> one global atomic per bin per block
// -> direct packed writes ((d&511)<<17 | s) into per-superbin regions.
// Scattered 4B writes land in runs of ~12 words; L2 absorbs them.
__global__ __launch_bounds__(K1_THREADS) void k1_bin_kernel(
        const int* __restrict__ idxi, const int* __restrict__ idxj,
        int* __restrict__ gcursor, int* __restrict__ ovfcnt,
        int* __restrict__ ovf, int* __restrict__ binbuf) {
    __shared__ int hist[NSB];
    __shared__ int gbase[NSB];
    __shared__ int cur[NSB];
    int t = threadIdx.x;
    if (t < NSB) hist[t] = 0;
    __syncthreads();

    int dd[K1_ITERS], ss[K1_ITERS];
    int e0 = blockIdx.x * K1_THREADS + t;
#pragma unroll
    for (int j = 0; j < K1_ITERS; ++j) {
        int e = e0 + j * K1_STRIDE;
        if (e < N_EDGES) {
            dd[j] = idxi[e];
            ss[j] = idxj[e];
            atomicAdd(&hist[dd[j] >> SB_SHIFT], 1);
        } else {
            dd[j] = -1;
        }
    }
    __syncthreads();

    if (t < NSB) {
        int h = hist[t];
        gbase[t] = h ? atomicAdd(&gcursor[t], h) : 0;
        cur[t] = 0;
    }
    __syncthreads();

#pragma unroll
    for (int j = 0; j < K1_ITERS; ++j) {
        if (dd[j] >= 0) {
            int b = dd[j] >> SB_SHIFT;
            int pos = gbase[b] + atomicAdd(&cur[b], 1);
            if (pos < SBCAP) {
                binbuf[b * SBCAP + pos] = ((dd[j] & (SB_NODES - 1)) << 17) | ss[j];
            } else {
                int op = atomicAdd(ovfcnt, 1);
                if (op < OVF_CAP) { ovf[2 * op] = dd[j]; ovf[2 * op + 1] = ss[j]; }
            }
        }
    }
}

// ============ k23: filter + wave-scan sort + shuffle-free gather ============
// One block per 64 nodes (1563 blocks x 256 thr = 6.1 blocks/CU, cap 8).
// Streams its superbin buffer once, ballot-compacts ~800 own entries to LDS,
// 64-wide wave scan (no barriers), counting sort, then gather with 16 lanes
// per node / 4 nodes per wave / 4 independent float4 loads in flight.
__global__ __launch_bounds__(256) void k23_gather_kernel(
        const float* __restrict__ x, const int* __restrict__ gcursor,
        const int* __restrict__ binbuf, int* __restrict__ ovfcnt,
        int* __restrict__ ovf, float* __restrict__ out) {
    __shared__ int cnt[NPB];
    __shared__ int excl[NPB];
    __shared__ int cur[NPB];
    __shared__ int klist[KCAP];
    __shared__ int srt[KCAP];
    __shared__ int nk;

    // bijective XCD swizzle (m204): 8 sibling blocks of a superbin share one XCD L2
    int bid = blockIdx.x;
    int nwg = NBLK;
    int xcd = bid & 7;
    int lid = bid >> 3;
    int q = nwg >> 3, r = nwg & 7;
    int blk = (xcd < r ? xcd * (q + 1) : r * (q + 1) + (xcd - r) * q) + lid;

    int t = threadIdx.x;
    int lane = t & 63;
    if (t < NPB) cnt[t] = 0;
    if (t == 0) nk = 0;
    __syncthreads();

    int sb  = blk >> 3;       // parent superbin
    int my3 = blk & 7;        // 64-node window within superbin
    int n = gcursor[sb];
    if (n > SBCAP) n = SBCAP;
    const int* buf = binbuf + (size_t)sb * SBCAP;

    // filter stream: keep entries whose dloc9>>6 == my window
    for (int i0 = 0; i0 < n; i0 += 256) {
        int i = i0 + t;
        int p = (i < n) ? buf[i] : -1;
        bool keep = (p >= 0) && ((p >> 23) == my3);
        unsigned long long m = __ballot(keep);
        int tot = __popcll(m);
        int base;
        if (lane == 0) base = atomicAdd(&nk, tot);
        base = __shfl(base, 0, 64);
        if (keep) {
            int pos = base + __popcll(m & ((1ull << lane) - 1));
            if (pos < KCAP) {
                klist[pos] = p;
                atomicAdd(&cnt[(p >> 17) & (NPB - 1)], 1);
            } else {
                int op = atomicAdd(ovfcnt, 1);
                if (op < OVF_CAP) {
                    ovf[2 * op]     = blk * NPB + ((p >> 17) & (NPB - 1));
                    ovf[2 * op + 1] = p & 0x1FFFF;
                }
            }
        }
    }
    __syncthreads();

    // 64-wide exclusive scan on wave 0 — no barriers inside
    if (t < NPB) {
        int v = cnt[t];
        int vinc = v;
#pragma unroll
        for (int off = 1; off < NPB; off <<= 1) {
            int u = __shfl_up(vinc, off, 64);
            if (lane >= off) vinc += u;
        }
        excl[t] = vinc - v;
        cur[t] = 0;
    }
    __syncthreads();

    // counting-sort scatter into srt (sources only)
    int kn = nk;
    if (kn > KCAP) kn = KCAP;
    for (int i = t; i < kn; i += 256) {
        int p = klist[i];
        int dl = (p >> 17) & (NPB - 1);
        int pos = excl[dl] + atomicAdd(&cur[dl], 1);
        srt[pos] = p & 0x1FFFF;
    }
    __syncthreads();

    // gather: wave w owns 16 nodes; each 16-lane sub owns 4 nodes sequentially.
    // 4 independent float4 loads per iteration, no cross-lane reduce, direct
    // coalesced 256B store per node.
    int wave = t >> 6;
    int sub  = lane >> 4;
    int c4   = lane & 15;
    const float4* xp = (const float4*)x;
    for (int nd = 0; nd < 4; ++nd) {
        int dl = wave * 16 + sub * 4 + nd;
        int node = blk * NPB + dl;
        int k = excl[dl];
        int end = k + cnt[dl];
        float4 acc = make_float4(0.f, 0.f, 0.f, 0.f);
        for (; k + 4 <= end; k += 4) {
            int s0 = srt[k], s1 = srt[k + 1], s2 = srt[k + 2], s3 = srt[k + 3];
            float4 v0 = xp[s0 * 16 + c4];
            float4 v1 = xp[s1 * 16 + c4];
            float4 v2 = xp[s2 * 16 + c4];
            float4 v3 = xp[s3 * 16 + c4];
            acc.x += (v0.x + v1.x) + (v2.x + v3.x);
            acc.y += (v0.y + v1.y) + (v2.y + v3.y);
            acc.z += (v0.z + v1.z) + (v2.z + v3.z);
            acc.w += (v0.w + v1.w) + (v2.w + v3.w);
        }
        for (; k < end; ++k) {
            float4 v0 = xp[srt[k] * 16 + c4];
            acc.x += v0.x; acc.y += v0.y; acc.z += v0.z; acc.w += v0.w;
        }
        if (node < N_NODES) {
            ((float4*)out)[(size_t)node * 16 + c4] = acc;
        }
    }
}

// Add any overflow edges (statistically none) on top of the gathered output.
__global__ __launch_bounds__(256) void ovf_fixup_kernel(
        const float* __restrict__ x, const int* __restrict__ ovfcnt,
        const int* __restrict__ ovf, float* __restrict__ out) {
    int n = *ovfcnt;
    if (n > OVF_CAP) n = OVF_CAP;
    long long total = (long long)n * 16;
    long long stride = (long long)gridDim.x * blockDim.x;
    for (long long t = blockIdx.x * blockDim.x + threadIdx.x; t < total; t += stride) {
        int e  = (int)(t >> 4);
        int fo = ((int)t & 15) << 2;
        int d = ovf[2 * e];
        int s = ovf[2 * e + 1];
        const float4 v = *(const float4*)(x + (size_t)s * D_FEAT + fo);
        float* o = out + (size_t)d * D_FEAT + fo;
        atomicAdd(o + 0, v.x);
        atomicAdd(o + 1, v.y);
        atomicAdd(o + 2, v.z);
        atomicAdd(o + 3, v.w);
    }
}

// ====================== fallback: atomic scatter-add ======================

__global__ __launch_bounds__(256) void zero_f4_kernel(float* __restrict__ out, int n4) {
    int i = blockIdx.x * blockDim.x + threadIdx.x;
    if (i < n4) ((float4*)out)[i] = make_float4(0.f, 0.f, 0.f, 0.f);
}

__global__ __launch_bounds__(256) void scatter_add_kernel(const float* __restrict__ x,
                                                          const int* __restrict__ idxi,
                                                          const int* __restrict__ idxj,
                                                          float* __restrict__ out) {
    int t = blockIdx.x * blockDim.x + threadIdx.x;
    int e = t >> 4;
    if (e >= N_EDGES) return;
    int fo = (t & 15) << 2;
    int dst = idxi[e];
    int src = idxj[e];
    const float4 v = *(const float4*)(x + (size_t)src * D_FEAT + fo);
    float* o = out + (size_t)dst * D_FEAT + fo;
    atomicAdd(o + 0, v.x);
    atomicAdd(o + 1, v.y);
    atomicAdd(o + 2, v.z);
    atomicAdd(o + 3, v.w);
}

extern "C" void kernel_launch(void* const* d_in, const int* in_sizes, int n_in,
                              void* d_out, int out_size, void* d_ws, size_t ws_size,
                              hipStream_t stream) {
    const float* x  = (const float*)d_in[0];
    const int*   ei = (const int*)d_in[1];   // flat (2, N_EDGES)
    const int*   idxi = ei;                  // row 0: destinations
    const int*   idxj = ei + N_EDGES;        // row 1: sources
    float* out = (float*)d_out;

    // --- primary: superbin scatter + filtered sort/gather ---
    // ws (ints): gcursor[256] | ovfcnt+pad[16] | ovf[2*OVF_CAP] | binbuf[NSB*SBCAP]
    {
        size_t need = (256 + 16 + 2 * (size_t)OVF_CAP +
                       (size_t)NSB * SBCAP) * sizeof(int);
        if (ws_size >= need) {
            int* gcursor = (int*)d_ws;
            int* ovfcnt  = gcursor + 256;
            int* ovf     = ovfcnt + 16;
            int* binbuf  = ovf + 2 * OVF_CAP;

            hipMemsetAsync(gcursor, 0, (256 + 16) * sizeof(int), stream);
            k1_bin_kernel<<<K1_BLOCKS, K1_THREADS, 0, stream>>>(idxi, idxj, gcursor,
                                                                ovfcnt, ovf, binbuf);
            k23_gather_kernel<<<NBLK, 256, 0, stream>>>(x, gcursor, binbuf,
                                                        ovfcnt, ovf, out);
            ovf_fixup_kernel<<<16, 256, 0, stream>>>(x, ovfcnt, ovf, out);
            return;
        }
    }

    // --- fallback: atomic scatter-add ---
    int n4 = (N_NODES * D_FEAT) / 4;
    zero_f4_kernel<<<(n4 + 255) / 256, 256, 0, stream>>>(out, n4);
    long long total_threads = (long long)N_EDGES * 16;
    scatter_add_kernel<<<(int)((total_threads + 255) / 256), 256, 0, stream>>>(x, idxi, idxj, out);
}